// Round 7
// baseline (290.043 us; speedup 1.0000x reference)
//
#include <hip/hip_runtime.h>
#include <hip/hip_bf16.h>

typedef unsigned short ushort_t;
typedef __attribute__((ext_vector_type(4))) float v4f;
typedef __attribute__((ext_vector_type(8))) short v8s;

#define FDIM 128
#define KCLUST 16
#define CSTRIDE 264   // comb row stride (ushorts) — proven in R5 phase B
#define NSTRIDE 136   // nrow/cenB row stride (ushorts): 272 B, 16B-aligned rows
#define QSTRIDE 40    // qmat/maskT row stride (ushorts): 80 B, 16B-aligned rows

__device__ __forceinline__ ushort_t f2bf(float x) {
    unsigned int u = __float_as_uint(x);
    unsigned int r = (u + 0x7fffu + ((u >> 16) & 1u)) >> 16;
    return (ushort_t)r;
}

__device__ __forceinline__ float wave_reduce_sum(float v) {
    #pragma unroll
    for (int off = 32; off > 0; off >>= 1) v += __shfl_xor(v, off, 64);
    return v;
}

// ---------------------------------------------------------------------------
// Kernel 1: cast weight (E x 256 f32) -> bf16, padded to Np rows (zeros).
// ---------------------------------------------------------------------------
__global__ void pack_weight(const float* __restrict__ W, ushort_t* __restrict__ Wb,
                            long total, long valid) {
    long i = ((long)blockIdx.x * blockDim.x + threadIdx.x) * 4;
    if (i >= total) return;
    float4 v;
    if (i < valid) v = *(const float4*)(W + i);
    else           v = make_float4(0.f, 0.f, 0.f, 0.f);
    ushort_t* dst = Wb + i;
    dst[0] = f2bf(v.x); dst[1] = f2bf(v.y); dst[2] = f2bf(v.z); dst[3] = f2bf(v.w);
}

// ---------------------------------------------------------------------------
// Kernel 2 (fused, MFMA phase A): 256 threads = 4 waves, one row b per wave.
// R6 post-mortem: maskT's k in [16,32) pad was uninitialized LDS; Q's zero
// pad times NaN garbage = NaN -> fmaxf(NaN,0)=0 -> silent all-zero output.
// EVERY LDS region an MFMA reads must be fully initialized, even where the
// other operand is zero. The pad-zero loop below is disjoint from the fill.
// ---------------------------------------------------------------------------
__global__ __launch_bounds__(256) void fused_agg(
    const int* __restrict__ nodes, const int* __restrict__ neigh_idx,
    const float* __restrict__ self_table, const float* __restrict__ neigh_table,
    const float* __restrict__ center, const float* __restrict__ cluster_mask,
    const float* __restrict__ alpha, const ushort_t* __restrict__ Wb,
    float* __restrict__ out, int B, int S, int E) {

    __shared__ __align__(16) ushort_t comb[16 * CSTRIDE];        // 8448 B
    __shared__ __align__(16) ushort_t nrow[4][16 * NSTRIDE];     // 17408 B
    __shared__ __align__(16) ushort_t cenB[16 * NSTRIDE];        // 4352 B
    __shared__ __align__(16) ushort_t maskT[FDIM * QSTRIDE];     // 10240 B
    __shared__ __align__(16) ushort_t aB[FDIM];                  // 256 B
    __shared__ __align__(16) ushort_t qmat[4][16 * QSTRIDE];     // 5120 B
    __shared__ __align__(16) float    n2w[4][16];                // 256 B
    __shared__ __align__(16) float    c2s[KCLUST];               // 64 B

    int t = threadIdx.x;
    int lane = t & 63, wave = t >> 6;
    int l16 = lane & 15, quad = lane >> 4;

    // ---- block setup (cooperative) ----
    for (int i = t; i < KCLUST * FDIM; i += 256) {
        int k = i >> 7, f = i & 127;
        cenB[k * NSTRIDE + f] = f2bf(center[i]);
        maskT[f * QSTRIDE + k] = f2bf(cluster_mask[i]);
    }
    // zero maskT pad: ushorts 16..39 of each row (dwords 8..19) — the MFMA
    // reads k up to 31; uninitialized garbage here was the R6 NaN bug.
    for (int i = t; i < FDIM * 12; i += 256) {
        int f = i / 12, c = i - f * 12;
        ((unsigned*)maskT)[f * (QSTRIDE / 2) + 8 + c] = 0u;
    }
    if (t < FDIM) aB[t] = f2bf(alpha[128 + t]);
    if (t < KCLUST) {
        const float4* cp = (const float4*)(center + t * FDIM);
        float acc = 0.f;
        #pragma unroll
        for (int j = 0; j < 32; j++) {
            float4 v = cp[j];
            acc += v.x * v.x + v.y * v.y + v.z * v.z + v.w * v.w;
        }
        c2s[t] = acc;
    }
    // zero comb rows 4..15 (padding rows of the m=16 phase-B tile)
    for (int i = t; i < (12 * CSTRIDE) / 2; i += 256)
        ((unsigned*)(comb + 4 * CSTRIDE))[i] = 0u;
    // zero qmat k=16..31 region of this wave (Q is 16x16 padded to K=32)
    {
        unsigned* qz = (unsigned*)(qmat[wave]);
        #pragma unroll
        for (int j = 0; j < 2; j++) {
            int d = lane + 64 * j;           // 128 dwords: 16 rows x 8
            int r = d >> 3, c = d & 7;
            qz[r * (QSTRIDE / 2) + 8 + c] = 0u;
        }
    }

    int b0 = blockIdx.x * 4;
    int b = b0 + wave;
    ushort_t* nr = nrow[wave];
    ushort_t* qm = qmat[wave];
    float* n2p = n2w[wave];
    ushort_t* crow = comb + wave * CSTRIDE;

    // ---- per-wave staging ----
    float ls = 0.f;
    if (b < B) {
        size_t node = (size_t)nodes[b];
        float s0 = self_table[node * FDIM + lane];
        float s1 = self_table[node * FDIM + 64 + lane];
        float as0 = alpha[lane], as1 = alpha[lane + 64];
        ls = wave_reduce_sum(s0 * as0 + s1 * as1);
        crow[lane] = f2bf(s0);
        crow[64 + lane] = f2bf(s1);
        const int* nidx = neigh_idx + (size_t)b * S;
        for (int s = 0; s < S; s++) {
            size_t g = (size_t)nidx[s];
            float2 v = *(const float2*)(neigh_table + g * FDIM + 2 * lane);
            unsigned pk = ((unsigned)f2bf(v.y) << 16) | (unsigned)f2bf(v.x);
            *(unsigned*)(nr + s * NSTRIDE + 2 * lane) = pk;
        }
        for (int s = S; s < 16; s++)
            *(unsigned*)(nr + s * NSTRIDE + 2 * lane) = 0u;
    } else {
        for (int s = 0; s < 16; s++)
            *(unsigned*)(nr + s * NSTRIDE + 2 * lane) = 0u;
        crow[lane] = 0; crow[64 + lane] = 0;
    }

    __syncthreads();   // setup + staging visible

    // ---- MFMA batch: cross / n2 / ln ----
    v8s afr[4], cfr[4], abf[4];
    #pragma unroll
    for (int kk = 0; kk < 4; kk++) {
        afr[kk] = *(const v8s*)(nr + l16 * NSTRIDE + kk * 32 + quad * 8);
        cfr[kk] = *(const v8s*)(cenB + l16 * NSTRIDE + kk * 32 + quad * 8);
        abf[kk] = *(const v8s*)(aB + kk * 32 + quad * 8);   // broadcast row
    }
    v4f cracc = {0.f, 0.f, 0.f, 0.f};
    v4f nnacc = {0.f, 0.f, 0.f, 0.f};
    v4f lnacc = {0.f, 0.f, 0.f, 0.f};
    #pragma unroll
    for (int kk = 0; kk < 4; kk++) {
        cracc = __builtin_amdgcn_mfma_f32_16x16x32_bf16(afr[kk], cfr[kk], cracc, 0, 0, 0);
        nnacc = __builtin_amdgcn_mfma_f32_16x16x32_bf16(afr[kk], afr[kk], nnacc, 0, 0, 0);
        lnacc = __builtin_amdgcn_mfma_f32_16x16x32_bf16(afr[kk], abf[kk], lnacc, 0, 0, 0);
    }
    // diag(NN) -> n2w[s]: lane where row(quad*4+r) == col(l16)
    if (quad == (l16 >> 2)) {
        int r = l16 & 3;
        float dv = (r == 0) ? nnacc[0] : (r == 1) ? nnacc[1] : (r == 2) ? nnacc[2] : nnacc[3];
        n2p[l16] = dv;
    }
    float c2l = c2s[l16];
    float4 n2q = *(const float4*)(n2p + quad * 4);   // n2 for s=quad*4..+3

    // ---- elementwise q (att folded, s>=S masked) ----
    float asum = 0.f, qv[4];
    #pragma unroll
    for (int r = 0; r < 4; r++) {
        int s = quad * 4 + r;
        float att = (s < S) ? __expf(fmaxf(ls + lnacc[r], 0.f)) : 0.f;
        asum += att;
        float d = n2q[r] - 2.f * cracc[r] + c2l + 1.f;
        qv[r] = __fdividef(att, d);
    }
    asum += __shfl_xor(asum, 16, 64);
    asum += __shfl_xor(asum, 32, 64);
    float inv = __fdividef(1.f, asum);
    #pragma unroll
    for (int r = 0; r < 4; r++)
        qm[(quad * 4 + r) * QSTRIDE + l16] = f2bf(qv[r]);

    // ---- M = Q @ maskT (K=32, padded) ----
    v8s qfr = *(const v8s*)(qm + l16 * QSTRIDE + quad * 8);
    v4f macc[8];
    #pragma unroll
    for (int fb = 0; fb < 8; fb++) {
        v8s mfr = *(const v8s*)(maskT + (fb * 16 + l16) * QSTRIDE + quad * 8);
        v4f z = {0.f, 0.f, 0.f, 0.f};
        macc[fb] = __builtin_amdgcn_mfma_f32_16x16x32_bf16(qfr, mfr, z, 0, 0, 0);
    }
    // ---- agg[f] = inv * sum_s M[s][f] * n[s][f] ----
    #pragma unroll
    for (int fb = 0; fb < 8; fb++) {
        float tacc = 0.f;
        #pragma unroll
        for (int r = 0; r < 4; r++) {
            int s = quad * 4 + r;
            ushort_t nv = nr[s * NSTRIDE + fb * 16 + l16];
            float nf = __uint_as_float((unsigned)nv << 16);
            tacc = fmaf(macc[fb][r], nf, tacc);
        }
        tacc += __shfl_xor(tacc, 16, 64);
        tacc += __shfl_xor(tacc, 32, 64);
        if ((fb & 3) == quad)
            crow[128 + fb * 16 + l16] = f2bf(tacc * inv);
    }
    __syncthreads();

    // ---------------- phase B (unchanged from R5) ----------------
    v8s bafr[8];
    #pragma unroll
    for (int kk = 0; kk < 8; kk++)
        bafr[kk] = *(const v8s*)(comb + l16 * CSTRIDE + kk * 32 + quad * 8);

    int Ntiles = (E + 15) >> 4;
    for (int nt = wave; nt < Ntiles; nt += 4) {
        const ushort_t* wrow = Wb + ((size_t)(nt * 16 + l16)) * 256 + quad * 8;
        v4f acc = {0.f, 0.f, 0.f, 0.f};
        #pragma unroll
        for (int kk = 0; kk < 8; kk++) {
            v8s bfr = *(const v8s*)(wrow + kk * 32);
            acc = __builtin_amdgcn_mfma_f32_16x16x32_bf16(bafr[kk], bfr, acc, 0, 0, 0);
        }
        int gcol = nt * 16 + l16;
        if (gcol < E) {
            #pragma unroll
            for (int rr = 0; rr < 4; rr++) {
                int r16 = quad * 4 + rr;
                if (r16 < 4) {
                    int grow = b0 + r16;
                    if (grow < B)
                        out[(size_t)grow * E + gcol] = fmaxf(acc[rr], 0.f);
                }
            }
        }
    }
}

extern "C" void kernel_launch(void* const* d_in, const int* in_sizes, int n_in,
                              void* d_out, int out_size, void* d_ws, size_t ws_size,
                              hipStream_t stream) {
    const int*   nodes        = (const int*)d_in[0];
    const int*   neigh_idx    = (const int*)d_in[1];
    const float* self_table   = (const float*)d_in[2];
    const float* neigh_table  = (const float*)d_in[3];
    const float* center       = (const float*)d_in[4];
    const float* cluster_mask = (const float*)d_in[5];
    const float* weight       = (const float*)d_in[6];
    const float* alpha        = (const float*)d_in[7];
    float* out = (float*)d_out;

    int B = in_sizes[0];
    int S = in_sizes[1] / B;
    int E = in_sizes[6] / (2 * FDIM);

    int Np = ((E + 15) / 16) * 16;
    ushort_t* Wb = (ushort_t*)d_ws;   // Np x 256 bf16

    long totalW = (long)Np * 256;
    long validW = (long)E * 256;
    int blksW = (int)((totalW + 1023) / 1024);
    pack_weight<<<blksW, 256, 0, stream>>>(weight, Wb, totalW, validW);

    int nblk = (B + 3) / 4;
    fused_agg<<<nblk, 256, 0, stream>>>(
        nodes, neigh_idx, self_table, neigh_table, center, cluster_mask, alpha,
        Wb, out, B, S, E);
}